// Round 4
// baseline (335.651 us; speedup 1.0000x reference)
//
#include <hip/hip_runtime.h>
#include <hip/hip_bf16.h>
#include <math.h>

#define N_NODES 50000
#define N_EDGES 800000
#define F_IN    256
#define HEADS   8
#define C1      32
#define F1      256   // HEADS*C1
#define C2      16
#define NEG     0.2f
#define EPSF    1e-16f
#define SCAN_B  196   // ceil(50000/256)

typedef __attribute__((ext_vector_type(8))) _Float16 half8;
typedef __attribute__((ext_vector_type(4))) _Float16 half4_t;
typedef __attribute__((ext_vector_type(4))) float    floatx4;

// ---------------- graph build: CSR by dst (self-loops included) -------------
// deg[] is memset to 0 by the host side; self-loop's +1 is folded into scans.

__global__ void k_hist(const int* __restrict__ ei, int* __restrict__ deg) {
    int i = blockIdx.x * blockDim.x + threadIdx.x;
    if (i < N_EDGES) atomicAdd(&deg[ei[N_EDGES + i]], 1);
}

// phase 1: per-block sums (deg+1 to account for self-loop)
__global__ __launch_bounds__(256) void k_scan1(const int* __restrict__ deg,
                                               int* __restrict__ bsum) {
    __shared__ int ws[4];
    int t = threadIdx.x, l = t & 63, w = t >> 6;
    int idx = blockIdx.x * 256 + t;
    int v = (idx < N_NODES) ? (deg[idx] + 1) : 0;
    #pragma unroll
    for (int m = 1; m < 64; m <<= 1) v += __shfl_xor(v, m, 64);
    if (l == 0) ws[w] = v;
    __syncthreads();
    if (t == 0) bsum[blockIdx.x] = ws[0] + ws[1] + ws[2] + ws[3];
}

// phase 2+3 fused: block computes its base from bsum, then local scan.
__global__ __launch_bounds__(256) void k_scan3(const int* __restrict__ deg,
                                               const int* __restrict__ bsum,
                                               int* __restrict__ offs,
                                               int* __restrict__ cursor) {
    __shared__ int rs[4];
    __shared__ int ws[4];
    int t = threadIdx.x, l = t & 63, w = t >> 6;
    // base = sum of bsum[j] for j < blockIdx.x   (SCAN_B=196 < 256)
    int p = (t < blockIdx.x) ? bsum[t] : 0;
    #pragma unroll
    for (int m = 1; m < 64; m <<= 1) p += __shfl_xor(p, m, 64);
    if (l == 0) rs[w] = p;

    int idx = blockIdx.x * 256 + t;
    int v = (idx < N_NODES) ? (deg[idx] + 1) : 0;
    int sv = v;
    #pragma unroll
    for (int off = 1; off < 64; off <<= 1) {
        int y = __shfl_up(sv, off, 64);
        if (l >= off) sv += y;
    }
    if (l == 63) ws[w] = sv;
    __syncthreads();
    int add = rs[0] + rs[1] + rs[2] + rs[3];
    for (int j = 0; j < w; ++j) add += ws[j];
    int exc = add + sv - v;
    if (idx < N_NODES) { offs[idx] = exc; cursor[idx] = exc; }
    if (idx == N_NODES - 1) offs[N_NODES] = exc + v;
}

__global__ void k_scatter(const int* __restrict__ ei, int* __restrict__ cursor,
                          int* __restrict__ ssrc) {
    int i = blockIdx.x * blockDim.x + threadIdx.x;
    const int total = N_EDGES + N_NODES;
    if (i >= total) return;
    int s, d;
    if (i < N_EDGES) { s = ei[i]; d = ei[N_EDGES + i]; }
    else             { s = d = i - N_EDGES; }
    int p = atomicAdd(&cursor[d], 1);
    ssrc[p] = s;
}

// ------------- weight prep: fp16, GEMM-friendly layouts --------------------
// Wp[kc][n][j] : kc = k>>5 (8 chunks), n = 0..255 col of W1, j = k&31.
// W2t[n][k]    : n = 0..15 col of W2.
__global__ void k_prep(const float* __restrict__ W1, const float* __restrict__ W2,
                       _Float16* __restrict__ Wp, _Float16* __restrict__ W2t) {
    int n = blockIdx.x;     // 0..256
    int k = threadIdx.x;    // 0..255
    if (n < 256) {
        float v = W1[k * 256 + n];
        Wp[(k >> 5) * 8192 + n * 32 + (k & 31)] = (_Float16)v;
    } else {
        for (int n2 = 0; n2 < 16; ++n2)
            W2t[n2 * 256 + k] = (_Float16)W2[k * 16 + n2];
    }
}

// ---------------- layer 1 GEMM via split-fp16 MFMA + fused att -------------
// h1h = fp16(x @ W1); als/ald computed from fp32 accumulators in epilogue.
// Block = 256 thr = 4 waves; tile 64 rows x 256 cols; B dbuf-staged in LDS.
__global__ __launch_bounds__(256) void k_gemm1(
        const float* __restrict__ x, const _Float16* __restrict__ Wp,
        const float* __restrict__ as1, const float* __restrict__ ad1,
        _Float16* __restrict__ h1h, float* __restrict__ als,
        float* __restrict__ ald) {
    __shared__ _Float16 sW[2][8192];
    int t = threadIdx.x;
    int w = t >> 6, l = t & 63;
    int lm = l & 15, q = l >> 4;
    int row0 = blockIdx.x * 64;
    int arow = row0 + w * 16 + lm;
    int rc = (arow < N_NODES) ? arow : (N_NODES - 1);
    const float* xp = x + (size_t)rc * 256 + q * 8;

    floatx4 acc[16];
    #pragma unroll
    for (int nt = 0; nt < 16; ++nt) acc[nt] = (floatx4){0.f, 0.f, 0.f, 0.f};

    auto stage = [&](int kc, int buf) {
        const char* g = (const char*)Wp + (size_t)kc * 16384;
        char* sp = (char*)&sW[buf][0];
        #pragma unroll
        for (int c = 0; c < 4; ++c)
            *(float4*)(sp + c * 4096 + t * 16) =
                *(const float4*)(g + c * 4096 + t * 16);
    };

    stage(0, 0);
    int buf = 0;
    #pragma unroll 1
    for (int kc = 0; kc < 8; ++kc) {
        __syncthreads();
        if (kc < 7) stage(kc + 1, buf ^ 1);

        float4 xa = *(const float4*)(xp + kc * 32);
        float4 xb = *(const float4*)(xp + kc * 32 + 4);
        float xv[8] = {xa.x, xa.y, xa.z, xa.w, xb.x, xb.y, xb.z, xb.w};
        half8 ah, al;
        #pragma unroll
        for (int j = 0; j < 8; ++j) {
            _Float16 h = (_Float16)xv[j];
            ah[j] = h;
            al[j] = (_Float16)(xv[j] - (float)h);
        }
        const _Float16* sb = &sW[buf][(size_t)lm * 32 + q * 8];
        #pragma unroll
        for (int nt = 0; nt < 16; ++nt) {
            half8 b = *(const half8*)(sb + nt * 512);
            acc[nt] = __builtin_amdgcn_mfma_f32_16x16x32_f16(ah, b, acc[nt], 0, 0, 0);
            acc[nt] = __builtin_amdgcn_mfma_f32_16x16x32_f16(al, b, acc[nt], 0, 0, 0);
        }
        buf ^= 1;
    }

    int rbase = row0 + w * 16 + q * 4;
    #pragma unroll
    for (int r = 0; r < 4; ++r) {
        int row = rbase + r;
        if (row < N_NODES) {
            size_t ro = (size_t)row * 256 + lm;
            #pragma unroll
            for (int nt = 0; nt < 16; ++nt)
                h1h[ro + nt * 16] = (_Float16)acc[nt][r];
        }
    }

    // fused attention coefficients: head h covers nt = 2h, 2h+1
    float as1v[16], ad1v[16];
    #pragma unroll
    for (int nt = 0; nt < 16; ++nt) {
        as1v[nt] = as1[nt * 16 + lm];
        ad1v[nt] = ad1[nt * 16 + lm];
    }
    #pragma unroll
    for (int r = 0; r < 4; ++r) {
        int row = rbase + r;
        bool ok = (row < N_NODES) && (lm == 0);
        #pragma unroll
        for (int h = 0; h < 8; ++h) {
            float vs = acc[2 * h][r] * as1v[2 * h] + acc[2 * h + 1][r] * as1v[2 * h + 1];
            float vd = acc[2 * h][r] * ad1v[2 * h] + acc[2 * h + 1][r] * ad1v[2 * h + 1];
            #pragma unroll
            for (int m = 1; m < 16; m <<= 1) {
                vs += __shfl_xor(vs, m, 64);
                vd += __shfl_xor(vd, m, 64);
            }
            if (ok) {
                als[row * 8 + h] = vs;
                ald[row * 8 + h] = vd;
            }
        }
    }
}

// ------------- layer 1 aggregation: one wave per dst node ------------------
// lanes 0..31 process even edges, 32..63 odd edges; lane covers 8 channels
// (head h = (l&31)>>2). One shfl_xor(32) merges the two halves at the end.
__global__ __launch_bounds__(64) void k_agg1(
        const int* __restrict__ offs, const int* __restrict__ ssrc,
        const _Float16* __restrict__ h1h, const float* __restrict__ als,
        const float* __restrict__ ald, const float* __restrict__ b1,
        _Float16* __restrict__ hposth) {
    __shared__ int   s_lds[64];
    __shared__ float w_lds[64 * 8];
    int l = threadIdx.x;
    int i = blockIdx.x;
    int sub = l >> 5, ll = l & 31;
    int h = ll >> 2;
    float4 ad0 = *(const float4*)(ald + i * 8);
    float4 ad1v = *(const float4*)(ald + i * 8 + 4);
    int beg = offs[i], end = offs[i + 1];
    float acc[8] = {0.f, 0.f, 0.f, 0.f, 0.f, 0.f, 0.f, 0.f};
    float dsum = 0.f;
    for (int c0 = beg; c0 < end; c0 += 64) {
        int nc = min(64, end - c0);
        __syncthreads();
        if (l < nc) {
            int s = ssrc[c0 + l];
            s_lds[l] = s;
            float4 s0 = *(const float4*)(als + s * 8);
            float4 s1 = *(const float4*)(als + s * 8 + 4);
            float e0 = s0.x + ad0.x,  e1 = s0.y + ad0.y;
            float e2 = s0.z + ad0.z,  e3 = s0.w + ad0.w;
            float e4 = s1.x + ad1v.x, e5 = s1.y + ad1v.y;
            float e6 = s1.z + ad1v.z, e7 = s1.w + ad1v.w;
            e0 = (e0 > 0.f) ? e0 : NEG * e0;  e1 = (e1 > 0.f) ? e1 : NEG * e1;
            e2 = (e2 > 0.f) ? e2 : NEG * e2;  e3 = (e3 > 0.f) ? e3 : NEG * e3;
            e4 = (e4 > 0.f) ? e4 : NEG * e4;  e5 = (e5 > 0.f) ? e5 : NEG * e5;
            e6 = (e6 > 0.f) ? e6 : NEG * e6;  e7 = (e7 > 0.f) ? e7 : NEG * e7;
            float4 w0 = make_float4(__expf(e0), __expf(e1), __expf(e2), __expf(e3));
            float4 w1 = make_float4(__expf(e4), __expf(e5), __expf(e6), __expf(e7));
            *(float4*)(w_lds + l * 8)     = w0;
            *(float4*)(w_lds + l * 8 + 4) = w1;
        }
        __syncthreads();
        #pragma unroll 2
        for (int e = sub; e < nc; e += 2) {
            float wv = w_lds[e * 8 + h];
            int s = s_lds[e];
            half8 hv = *(const half8*)(h1h + (size_t)s * 256 + 8 * ll);
            #pragma unroll
            for (int j = 0; j < 8; ++j) acc[j] += wv * (float)hv[j];
            dsum += wv;
        }
    }
    #pragma unroll
    for (int j = 0; j < 8; ++j) acc[j] += __shfl_xor(acc[j], 32, 64);
    dsum += __shfl_xor(dsum, 32, 64);
    if (sub == 0) {
        float dn = 1.0f / (dsum + EPSF);
        float4 b4a = *(const float4*)(b1 + 8 * ll);
        float4 b4b = *(const float4*)(b1 + 8 * ll + 4);
        float bb[8] = {b4a.x, b4a.y, b4a.z, b4a.w, b4b.x, b4b.y, b4b.z, b4b.w};
        half8 o;
        #pragma unroll
        for (int j = 0; j < 8; ++j) {
            float v = acc[j] * dn + bb[j];
            v = (v > 0.f) ? v : (__expf(v) - 1.f);
            o[j] = (_Float16)v;
        }
        *(half8*)(hposth + (size_t)i * 256 + 8 * ll) = o;
    }
}

// ---------------- layer 2 GEMM via fp16 MFMA + fused att2 ------------------
// h2h = fp16(hpost @ W2), als2/ald2 fused. 4 waves x 16 rows per block.
__global__ __launch_bounds__(256) void k_gemm2(
        const _Float16* __restrict__ hposth, const _Float16* __restrict__ W2t,
        const float* __restrict__ as2, const float* __restrict__ ad2,
        _Float16* __restrict__ h2h, float* __restrict__ als2,
        float* __restrict__ ald2) {
    int t = threadIdx.x;
    int w = t >> 6, l = t & 63;
    int lm = l & 15, q = l >> 4;
    int row0 = blockIdx.x * 64;
    int arow = row0 + w * 16 + lm;
    int rc = (arow < N_NODES) ? arow : (N_NODES - 1);
    const _Float16* ap = hposth + (size_t)rc * 256 + q * 8;
    const _Float16* bp = W2t + (size_t)lm * 256 + q * 8;

    floatx4 acc = (floatx4){0.f, 0.f, 0.f, 0.f};
    #pragma unroll
    for (int kc = 0; kc < 8; ++kc) {
        half8 a = *(const half8*)(ap + kc * 32);
        half8 b = *(const half8*)(bp + kc * 32);
        acc = __builtin_amdgcn_mfma_f32_16x16x32_f16(a, b, acc, 0, 0, 0);
    }

    float a_s = as2[lm], a_d = ad2[lm];
    int rbase = row0 + w * 16 + q * 4;
    #pragma unroll
    for (int r = 0; r < 4; ++r) {
        int row = rbase + r;
        float v = acc[r];
        float vs = v * a_s, vd = v * a_d;
        #pragma unroll
        for (int m = 1; m < 16; m <<= 1) {
            vs += __shfl_xor(vs, m, 64);
            vd += __shfl_xor(vd, m, 64);
        }
        if (row < N_NODES) {
            h2h[row * C2 + lm] = (_Float16)v;
            if (lm == 0) { als2[row] = vs; ald2[row] = vd; }
        }
    }
}

// ---------------- layer 2 aggregation -> out (shuffle-only) ----------------
// 4 nodes per block (one wave each). lane: c = l&15 channel, es = l>>4 slice.
__global__ __launch_bounds__(256) void k_agg2(
        const int* __restrict__ offs, const int* __restrict__ ssrc,
        const _Float16* __restrict__ h2h, const float* __restrict__ als2,
        const float* __restrict__ ald2, const float* __restrict__ b2,
        float* __restrict__ out) {
    int t = threadIdx.x;
    int l = t & 63;
    int i = blockIdx.x * 4 + (t >> 6);
    int c = l & 15, es = l >> 4;
    float adi = ald2[i];
    int beg = offs[i], end = offs[i + 1];
    float acc = 0.f, dsum = 0.f;
    for (int c0 = beg; c0 < end; c0 += 64) {
        int nc = min(64, end - c0);
        int s = 0; float wv = 0.f;
        if (l < nc) {
            s = ssrc[c0 + l];
            float v = als2[s] + adi;
            v = (v > 0.f) ? v : NEG * v;
            wv = __expf(v);
            dsum += wv;
        }
        for (int e0 = 0; e0 < nc; e0 += 4) {     // uniform trip count
            int e = e0 + es;
            int ec = (e < nc) ? e : (nc - 1);
            int se = __shfl(s, ec, 64);
            float we = __shfl(wv, ec, 64);
            if (e < nc) acc += we * (float)h2h[(size_t)se * C2 + c];
        }
    }
    #pragma unroll
    for (int m = 1; m < 64; m <<= 1) dsum += __shfl_xor(dsum, m, 64);
    acc += __shfl_xor(acc, 16, 64);
    acc += __shfl_xor(acc, 32, 64);
    if (l < 16) out[i * C2 + l] = acc / (dsum + EPSF) + b2[l];
}

// ---------------------------------------------------------------------------

extern "C" void kernel_launch(void* const* d_in, const int* in_sizes, int n_in,
                              void* d_out, int out_size, void* d_ws, size_t ws_size,
                              hipStream_t stream) {
    const float* x   = (const float*)d_in[0];
    const int*   ei  = (const int*)d_in[1];
    const float* W1  = (const float*)d_in[2];
    const float* as1 = (const float*)d_in[3];
    const float* ad1 = (const float*)d_in[4];
    const float* b1  = (const float*)d_in[5];
    const float* W2  = (const float*)d_in[6];
    const float* as2 = (const float*)d_in[7];
    const float* ad2 = (const float*)d_in[8];
    const float* b2  = (const float*)d_in[9];
    float* out = (float*)d_out;

    char* ws = (char*)d_ws;
    size_t off = 0;
    auto alloc = [&](size_t bytes) {
        off = (off + 255) & ~(size_t)255;
        void* p = ws + off;
        off += bytes;
        return p;
    };
    _Float16* h1h    = (_Float16*)alloc((size_t)N_NODES * F1 * 2);
    _Float16* hposth = (_Float16*)alloc((size_t)N_NODES * F1 * 2);
    _Float16* h2h    = (_Float16*)alloc((size_t)N_NODES * C2 * 2);
    float* als   = (float*)alloc((size_t)N_NODES * HEADS * 4);
    float* ald   = (float*)alloc((size_t)N_NODES * HEADS * 4);
    float* als2  = (float*)alloc((size_t)N_NODES * 4);
    float* ald2  = (float*)alloc((size_t)N_NODES * 4);
    int*   deg   = (int*)alloc((size_t)N_NODES * 4);
    int*   offs  = (int*)alloc((size_t)(N_NODES + 1) * 4);
    int*   cursor= (int*)alloc((size_t)N_NODES * 4);
    int*   bsum  = (int*)alloc((size_t)SCAN_B * 4);
    int*   ssrc  = (int*)alloc((size_t)(N_EDGES + N_NODES) * 4);
    _Float16* Wp  = (_Float16*)alloc((size_t)256 * 256 * 2);
    _Float16* W2t = (_Float16*)alloc((size_t)16 * 256 * 2);
    (void)ws_size; (void)in_sizes; (void)n_in; (void)out_size;

    hipMemsetAsync(deg, 0, (size_t)N_NODES * 4, stream);
    k_hist<<<(N_EDGES + 255) / 256, 256, 0, stream>>>(ei, deg);
    k_scan1<<<SCAN_B, 256, 0, stream>>>(deg, bsum);
    k_scan3<<<SCAN_B, 256, 0, stream>>>(deg, bsum, offs, cursor);
    k_scatter<<<(N_EDGES + N_NODES + 255) / 256, 256, 0, stream>>>(ei, cursor, ssrc);
    k_prep<<<257, 256, 0, stream>>>(W1, W2, Wp, W2t);
    k_gemm1<<<(N_NODES + 63) / 64, 256, 0, stream>>>(x, Wp, as1, ad1, h1h, als, ald);
    k_agg1<<<N_NODES, 64, 0, stream>>>(offs, ssrc, h1h, als, ald, b1, hposth);
    k_gemm2<<<(N_NODES + 63) / 64, 256, 0, stream>>>(hposth, W2t, as2, ad2, h2h, als2, ald2);
    k_agg2<<<N_NODES / 4, 256, 0, stream>>>(offs, ssrc, h2h, als2, ald2, b2, out);
}

// Round 5
// 331.492 us; speedup vs baseline: 1.0125x; 1.0125x over previous
//
#include <hip/hip_runtime.h>
#include <hip/hip_bf16.h>
#include <math.h>

#define N_NODES 50000
#define N_EDGES 800000
#define F_IN    256
#define HEADS   8
#define C1      32
#define F1      256   // HEADS*C1
#define C2      16
#define NEG     0.2f
#define EPSF    1e-16f
#define SCAN_B  196   // ceil(50000/256)
// Wp: 8 k-chunks x 272 n-cols x 32 k-elems (cols 256..271 = fused att cols)
#define WP_KC_STRIDE 8704   // 272*32 halves
#define WP_KC_BYTES  17408

typedef __attribute__((ext_vector_type(8))) _Float16 half8;
typedef __attribute__((ext_vector_type(4))) _Float16 half4_t;
typedef __attribute__((ext_vector_type(4))) float    floatx4;

// ---------------- graph build: CSR by dst (self-loops included) -------------
// deg[] is memset to 0 host-side; self-loop's +1 folded into the scans.

__global__ void k_hist(const int* __restrict__ ei, int* __restrict__ deg) {
    int i = blockIdx.x * blockDim.x + threadIdx.x;
    if (i < N_EDGES) atomicAdd(&deg[ei[N_EDGES + i]], 1);
}

__global__ __launch_bounds__(256) void k_scan1(const int* __restrict__ deg,
                                               int* __restrict__ bsum) {
    __shared__ int ws[4];
    int t = threadIdx.x, l = t & 63, w = t >> 6;
    int idx = blockIdx.x * 256 + t;
    int v = (idx < N_NODES) ? (deg[idx] + 1) : 0;
    #pragma unroll
    for (int m = 1; m < 64; m <<= 1) v += __shfl_xor(v, m, 64);
    if (l == 0) ws[w] = v;
    __syncthreads();
    if (t == 0) bsum[blockIdx.x] = ws[0] + ws[1] + ws[2] + ws[3];
}

__global__ __launch_bounds__(256) void k_scan3(const int* __restrict__ deg,
                                               const int* __restrict__ bsum,
                                               int* __restrict__ offs,
                                               int* __restrict__ cursor) {
    __shared__ int rs[4];
    __shared__ int ws[4];
    int t = threadIdx.x, l = t & 63, w = t >> 6;
    int p = (t < blockIdx.x) ? bsum[t] : 0;    // SCAN_B=196 < 256
    #pragma unroll
    for (int m = 1; m < 64; m <<= 1) p += __shfl_xor(p, m, 64);
    if (l == 0) rs[w] = p;

    int idx = blockIdx.x * 256 + t;
    int v = (idx < N_NODES) ? (deg[idx] + 1) : 0;
    int sv = v;
    #pragma unroll
    for (int off = 1; off < 64; off <<= 1) {
        int y = __shfl_up(sv, off, 64);
        if (l >= off) sv += y;
    }
    if (l == 63) ws[w] = sv;
    __syncthreads();
    int add = rs[0] + rs[1] + rs[2] + rs[3];
    for (int j = 0; j < w; ++j) add += ws[j];
    int exc = add + sv - v;
    if (idx < N_NODES) { offs[idx] = exc; cursor[idx] = exc; }
    if (idx == N_NODES - 1) offs[N_NODES] = exc + v;
}

__global__ void k_scatter(const int* __restrict__ ei, int* __restrict__ cursor,
                          int* __restrict__ ssrc) {
    int i = blockIdx.x * blockDim.x + threadIdx.x;
    const int total = N_EDGES + N_NODES;
    if (i >= total) return;
    int s, d;
    if (i < N_EDGES) { s = ei[i]; d = ei[N_EDGES + i]; }
    else             { s = d = i - N_EDGES; }
    int p = atomicAdd(&cursor[d], 1);
    ssrc[p] = s;
}

// ------------- weight prep ------------------------------------------------
// Wp[kc][n'][j]: n'=0..255 -> W1 col n'; n'=256..263 -> Wa_src head; 264..271
// -> Wa_dst head, where Wa[:,h] = W1[:, h*32:+32] @ a[h,:]  (als = x @ Wa).
__global__ void k_prep(const float* __restrict__ W1, const float* __restrict__ W2,
                       const float* __restrict__ as1, const float* __restrict__ ad1,
                       _Float16* __restrict__ Wp, _Float16* __restrict__ W2t) {
    int n = blockIdx.x;     // 0..256
    int k = threadIdx.x;    // 0..255
    if (n < 256) {
        float v = W1[k * 256 + n];
        Wp[(k >> 5) * WP_KC_STRIDE + n * 32 + (k & 31)] = (_Float16)v;
    } else {
        for (int n2 = 0; n2 < 16; ++n2)
            W2t[n2 * 256 + k] = (_Float16)W2[k * 16 + n2];
        const float* wrow = W1 + (size_t)k * 256;
        for (int h = 0; h < 8; ++h) {
            float ss = 0.f, sd = 0.f;
            for (int c = 0; c < 32; ++c) {
                float wv = wrow[h * 32 + c];
                ss += wv * as1[h * 32 + c];
                sd += wv * ad1[h * 32 + c];
            }
            Wp[(k >> 5) * WP_KC_STRIDE + (256 + h) * 32 + (k & 31)] = (_Float16)ss;
            Wp[(k >> 5) * WP_KC_STRIDE + (264 + h) * 32 + (k & 31)] = (_Float16)sd;
        }
    }
}

// ---------------- layer 1 GEMM via split-fp16 MFMA, att via 17th tile ------
// h1h = fp16(x @ W1); als/ald = x @ Wa from acc[16] directly (no shuffles).
__global__ __launch_bounds__(256) void k_gemm1(
        const float* __restrict__ x, const _Float16* __restrict__ Wp,
        _Float16* __restrict__ h1h, float* __restrict__ als,
        float* __restrict__ ald) {
    __shared__ _Float16 sW[2][WP_KC_STRIDE];
    int t = threadIdx.x;
    int w = t >> 6, l = t & 63;
    int lm = l & 15, q = l >> 4;
    int row0 = blockIdx.x * 64;
    int arow = row0 + w * 16 + lm;
    int rc = (arow < N_NODES) ? arow : (N_NODES - 1);
    const float* xp = x + (size_t)rc * 256 + q * 8;

    floatx4 acc[17];
    #pragma unroll
    for (int nt = 0; nt < 17; ++nt) acc[nt] = (floatx4){0.f, 0.f, 0.f, 0.f};

    auto stage = [&](int kc, int buf) {
        const char* g = (const char*)Wp + (size_t)kc * WP_KC_BYTES;
        char* sp = (char*)&sW[buf][0];
        #pragma unroll
        for (int c = 0; c < 4; ++c)
            *(float4*)(sp + c * 4096 + t * 16) =
                *(const float4*)(g + c * 4096 + t * 16);
        if (t < 64)
            *(float4*)(sp + 16384 + t * 16) =
                *(const float4*)(g + 16384 + t * 16);
    };

    stage(0, 0);
    int buf = 0;
    #pragma unroll 1
    for (int kc = 0; kc < 8; ++kc) {
        __syncthreads();
        if (kc < 7) stage(kc + 1, buf ^ 1);

        float4 xa = *(const float4*)(xp + kc * 32);
        float4 xb = *(const float4*)(xp + kc * 32 + 4);
        float xv[8] = {xa.x, xa.y, xa.z, xa.w, xb.x, xb.y, xb.z, xb.w};
        half8 ah, al;
        #pragma unroll
        for (int j = 0; j < 8; ++j) {
            _Float16 h = (_Float16)xv[j];
            ah[j] = h;
            al[j] = (_Float16)(xv[j] - (float)h);
        }
        const _Float16* sb = &sW[buf][(size_t)lm * 32 + q * 8];
        #pragma unroll
        for (int nt = 0; nt < 17; ++nt) {
            half8 b = *(const half8*)(sb + nt * 512);
            acc[nt] = __builtin_amdgcn_mfma_f32_16x16x32_f16(ah, b, acc[nt], 0, 0, 0);
            acc[nt] = __builtin_amdgcn_mfma_f32_16x16x32_f16(al, b, acc[nt], 0, 0, 0);
        }
        buf ^= 1;
    }

    int rbase = row0 + w * 16 + q * 4;
    #pragma unroll
    for (int r = 0; r < 4; ++r) {
        int row = rbase + r;
        if (row < N_NODES) {
            size_t ro = (size_t)row * 256 + lm;
            #pragma unroll
            for (int nt = 0; nt < 16; ++nt)
                h1h[ro + nt * 16] = (_Float16)acc[nt][r];
            float av = acc[16][r];
            if (lm < 8) als[row * 8 + lm] = av;
            else        ald[row * 8 + (lm - 8)] = av;
        }
    }
}

// ------------- layer 1 aggregation: one wave per dst node ------------------
// lanes 0..31 = even edges, 32..63 = odd edges; lane covers 8 channels.
// Inner loop batches 4 independent row-gathers to raise MLP.
__global__ __launch_bounds__(64) void k_agg1(
        const int* __restrict__ offs, const int* __restrict__ ssrc,
        const _Float16* __restrict__ h1h, const float* __restrict__ als,
        const float* __restrict__ ald, const float* __restrict__ b1,
        _Float16* __restrict__ hposth) {
    __shared__ int   s_lds[64];
    __shared__ float w_lds[64 * 8];
    int l = threadIdx.x;
    int i = blockIdx.x;
    int sub = l >> 5, ll = l & 31;
    int h = ll >> 2;
    float4 ad0 = *(const float4*)(ald + i * 8);
    float4 ad1v = *(const float4*)(ald + i * 8 + 4);
    int beg = offs[i], end = offs[i + 1];
    float acc[8] = {0.f, 0.f, 0.f, 0.f, 0.f, 0.f, 0.f, 0.f};
    float dsum = 0.f;
    const size_t cbase = 8 * (size_t)ll;
    for (int c0 = beg; c0 < end; c0 += 64) {
        int nc = min(64, end - c0);
        __syncthreads();
        if (l < nc) {
            int s = ssrc[c0 + l];
            s_lds[l] = s;
            float4 s0 = *(const float4*)(als + s * 8);
            float4 s1 = *(const float4*)(als + s * 8 + 4);
            float e0 = s0.x + ad0.x,  e1 = s0.y + ad0.y;
            float e2 = s0.z + ad0.z,  e3 = s0.w + ad0.w;
            float e4 = s1.x + ad1v.x, e5 = s1.y + ad1v.y;
            float e6 = s1.z + ad1v.z, e7 = s1.w + ad1v.w;
            e0 = (e0 > 0.f) ? e0 : NEG * e0;  e1 = (e1 > 0.f) ? e1 : NEG * e1;
            e2 = (e2 > 0.f) ? e2 : NEG * e2;  e3 = (e3 > 0.f) ? e3 : NEG * e3;
            e4 = (e4 > 0.f) ? e4 : NEG * e4;  e5 = (e5 > 0.f) ? e5 : NEG * e5;
            e6 = (e6 > 0.f) ? e6 : NEG * e6;  e7 = (e7 > 0.f) ? e7 : NEG * e7;
            float4 w0 = make_float4(__expf(e0), __expf(e1), __expf(e2), __expf(e3));
            float4 w1 = make_float4(__expf(e4), __expf(e5), __expf(e6), __expf(e7));
            *(float4*)(w_lds + l * 8)     = w0;
            *(float4*)(w_lds + l * 8 + 4) = w1;
        }
        __syncthreads();
        int e = sub;
        for (; e + 6 < nc; e += 8) {     // 4 edges in flight for this half
            int s0 = s_lds[e],     s1 = s_lds[e + 2];
            int s2 = s_lds[e + 4], s3 = s_lds[e + 6];
            float w0 = w_lds[e * 8 + h],       w1 = w_lds[(e + 2) * 8 + h];
            float w2 = w_lds[(e + 4) * 8 + h], w3 = w_lds[(e + 6) * 8 + h];
            half8 v0 = *(const half8*)(h1h + (size_t)s0 * 256 + cbase);
            half8 v1 = *(const half8*)(h1h + (size_t)s1 * 256 + cbase);
            half8 v2 = *(const half8*)(h1h + (size_t)s2 * 256 + cbase);
            half8 v3 = *(const half8*)(h1h + (size_t)s3 * 256 + cbase);
            #pragma unroll
            for (int j = 0; j < 8; ++j)
                acc[j] += w0 * (float)v0[j] + w1 * (float)v1[j]
                        + w2 * (float)v2[j] + w3 * (float)v3[j];
            dsum += w0 + w1 + w2 + w3;
        }
        for (; e < nc; e += 2) {
            float wv = w_lds[e * 8 + h];
            int s = s_lds[e];
            half8 hv = *(const half8*)(h1h + (size_t)s * 256 + cbase);
            #pragma unroll
            for (int j = 0; j < 8; ++j) acc[j] += wv * (float)hv[j];
            dsum += wv;
        }
    }
    #pragma unroll
    for (int j = 0; j < 8; ++j) acc[j] += __shfl_xor(acc[j], 32, 64);
    dsum += __shfl_xor(dsum, 32, 64);
    if (sub == 0) {
        float dn = 1.0f / (dsum + EPSF);
        float4 b4a = *(const float4*)(b1 + 8 * ll);
        float4 b4b = *(const float4*)(b1 + 8 * ll + 4);
        float bb[8] = {b4a.x, b4a.y, b4a.z, b4a.w, b4b.x, b4b.y, b4b.z, b4b.w};
        half8 o;
        #pragma unroll
        for (int j = 0; j < 8; ++j) {
            float v = acc[j] * dn + bb[j];
            v = (v > 0.f) ? v : (__expf(v) - 1.f);
            o[j] = (_Float16)v;
        }
        *(half8*)(hposth + (size_t)i * 256 + cbase) = o;
    }
}

// ---------------- layer 2 GEMM via fp16 MFMA + fused att2 ------------------
__global__ __launch_bounds__(256) void k_gemm2(
        const _Float16* __restrict__ hposth, const _Float16* __restrict__ W2t,
        const float* __restrict__ as2, const float* __restrict__ ad2,
        _Float16* __restrict__ h2h, float* __restrict__ als2,
        float* __restrict__ ald2) {
    int t = threadIdx.x;
    int w = t >> 6, l = t & 63;
    int lm = l & 15, q = l >> 4;
    int row0 = blockIdx.x * 64;
    int arow = row0 + w * 16 + lm;
    int rc = (arow < N_NODES) ? arow : (N_NODES - 1);
    const _Float16* ap = hposth + (size_t)rc * 256 + q * 8;
    const _Float16* bp = W2t + (size_t)lm * 256 + q * 8;

    floatx4 acc = (floatx4){0.f, 0.f, 0.f, 0.f};
    #pragma unroll
    for (int kc = 0; kc < 8; ++kc) {
        half8 a = *(const half8*)(ap + kc * 32);
        half8 b = *(const half8*)(bp + kc * 32);
        acc = __builtin_amdgcn_mfma_f32_16x16x32_f16(a, b, acc, 0, 0, 0);
    }

    float a_s = as2[lm], a_d = ad2[lm];
    int rbase = row0 + w * 16 + q * 4;
    #pragma unroll
    for (int r = 0; r < 4; ++r) {
        int row = rbase + r;
        float v = acc[r];
        float vs = v * a_s, vd = v * a_d;
        #pragma unroll
        for (int m = 1; m < 16; m <<= 1) {
            vs += __shfl_xor(vs, m, 64);
            vd += __shfl_xor(vd, m, 64);
        }
        if (row < N_NODES) {
            h2h[row * C2 + lm] = (_Float16)v;
            if (lm == 0) { als2[row] = vs; ald2[row] = vd; }
        }
    }
}

// ---------------- layer 2 aggregation -> out (shuffle-only) ----------------
__global__ __launch_bounds__(256) void k_agg2(
        const int* __restrict__ offs, const int* __restrict__ ssrc,
        const _Float16* __restrict__ h2h, const float* __restrict__ als2,
        const float* __restrict__ ald2, const float* __restrict__ b2,
        float* __restrict__ out) {
    int t = threadIdx.x;
    int l = t & 63;
    int i = blockIdx.x * 4 + (t >> 6);
    int c = l & 15, es = l >> 4;
    float adi = ald2[i];
    int beg = offs[i], end = offs[i + 1];
    float acc = 0.f, dsum = 0.f;
    for (int c0 = beg; c0 < end; c0 += 64) {
        int nc = min(64, end - c0);
        int s = 0; float wv = 0.f;
        if (l < nc) {
            s = ssrc[c0 + l];
            float v = als2[s] + adi;
            v = (v > 0.f) ? v : NEG * v;
            wv = __expf(v);
            dsum += wv;
        }
        for (int e0 = 0; e0 < nc; e0 += 4) {     // uniform trip count
            int e = e0 + es;
            int ec = (e < nc) ? e : (nc - 1);
            int se = __shfl(s, ec, 64);
            float we = __shfl(wv, ec, 64);
            if (e < nc) acc += we * (float)h2h[(size_t)se * C2 + c];
        }
    }
    #pragma unroll
    for (int m = 1; m < 64; m <<= 1) dsum += __shfl_xor(dsum, m, 64);
    acc += __shfl_xor(acc, 16, 64);
    acc += __shfl_xor(acc, 32, 64);
    if (l < 16) out[i * C2 + l] = acc / (dsum + EPSF) + b2[l];
}

// ---------------------------------------------------------------------------

extern "C" void kernel_launch(void* const* d_in, const int* in_sizes, int n_in,
                              void* d_out, int out_size, void* d_ws, size_t ws_size,
                              hipStream_t stream) {
    const float* x   = (const float*)d_in[0];
    const int*   ei  = (const int*)d_in[1];
    const float* W1  = (const float*)d_in[2];
    const float* as1 = (const float*)d_in[3];
    const float* ad1 = (const float*)d_in[4];
    const float* b1  = (const float*)d_in[5];
    const float* W2  = (const float*)d_in[6];
    const float* as2 = (const float*)d_in[7];
    const float* ad2 = (const float*)d_in[8];
    const float* b2  = (const float*)d_in[9];
    float* out = (float*)d_out;

    char* ws = (char*)d_ws;
    size_t off = 0;
    auto alloc = [&](size_t bytes) {
        off = (off + 255) & ~(size_t)255;
        void* p = ws + off;
        off += bytes;
        return p;
    };
    _Float16* h1h    = (_Float16*)alloc((size_t)N_NODES * F1 * 2);
    _Float16* hposth = (_Float16*)alloc((size_t)N_NODES * F1 * 2);
    _Float16* h2h    = (_Float16*)alloc((size_t)N_NODES * C2 * 2);
    float* als   = (float*)alloc((size_t)N_NODES * HEADS * 4);
    float* ald   = (float*)alloc((size_t)N_NODES * HEADS * 4);
    float* als2  = (float*)alloc((size_t)N_NODES * 4);
    float* ald2  = (float*)alloc((size_t)N_NODES * 4);
    int*   deg   = (int*)alloc((size_t)N_NODES * 4);
    int*   offs  = (int*)alloc((size_t)(N_NODES + 1) * 4);
    int*   cursor= (int*)alloc((size_t)N_NODES * 4);
    int*   bsum  = (int*)alloc((size_t)SCAN_B * 4);
    int*   ssrc  = (int*)alloc((size_t)(N_EDGES + N_NODES) * 4);
    _Float16* Wp  = (_Float16*)alloc((size_t)8 * WP_KC_STRIDE * 2);
    _Float16* W2t = (_Float16*)alloc((size_t)16 * 256 * 2);
    (void)ws_size; (void)in_sizes; (void)n_in; (void)out_size;

    hipMemsetAsync(deg, 0, (size_t)N_NODES * 4, stream);
    k_hist<<<(N_EDGES + 255) / 256, 256, 0, stream>>>(ei, deg);
    k_scan1<<<SCAN_B, 256, 0, stream>>>(deg, bsum);
    k_scan3<<<SCAN_B, 256, 0, stream>>>(deg, bsum, offs, cursor);
    k_scatter<<<(N_EDGES + N_NODES + 255) / 256, 256, 0, stream>>>(ei, cursor, ssrc);
    k_prep<<<257, 256, 0, stream>>>(W1, W2, as1, ad1, Wp, W2t);
    k_gemm1<<<(N_NODES + 63) / 64, 256, 0, stream>>>(x, Wp, h1h, als, ald);
    k_agg1<<<N_NODES, 64, 0, stream>>>(offs, ssrc, h1h, als, ald, b1, hposth);
    k_gemm2<<<(N_NODES + 63) / 64, 256, 0, stream>>>(hposth, W2t, as2, ad2, h2h, als2, ald2);
    k_agg2<<<N_NODES / 4, 256, 0, stream>>>(offs, ssrc, h2h, als2, ald2, b2, out);
}